// Round 4
// baseline (189.377 us; speedup 1.0000x reference)
//
#include <hip/hip_runtime.h>
#include <math.h>

#define BB 4
#define NSZ 2048
#define FDIM 128
#define ODIM 32
#define HH 8

typedef short short8 __attribute__((ext_vector_type(8)));
typedef float f32x4 __attribute__((ext_vector_type(4)));

// workspace layout (float units)
#define WS_EAP  0                 // float2[B*H*N] (EA, EA2)   = 131072 floats
#define WS_EBP  131072            // float2[B*H*N] (EB, EB2)   = 131072 floats
#define WS_ADJB 262144            // [B][N][64] u32            = 524288 words
#define WS_WHF  786432            // bf16 B-fragments          = 1048576 floats
// whf layout: int4[ ((b*H+h)*64 + jt)*2 + ot ][ 64 lanes ]  (16 B per lane-frag)

// round-to-nearest-even float -> bf16, result in TOP 16 bits
__device__ __forceinline__ unsigned bfbits(float f) {
    unsigned u = __builtin_bit_cast(unsigned, f);
    return u + 0x7fffu + ((u >> 16) & 1u);
}

// ---------------------------------------------------------------------------
// Fused prep kernel. Blocks [0,16384): adj bitmask pack (HBM stream — starts
// first). Blocks [16384,17408): Wh projection + whf fragment pack + alpha exps.
// ---------------------------------------------------------------------------
__global__ __launch_bounds__(256) void k_prep(const float* __restrict__ x,
                                              const float* __restrict__ adj,
                                              const float* __restrict__ W,
                                              const float* __restrict__ a_src,
                                              const float* __restrict__ a_dst,
                                              unsigned* __restrict__ adjb,
                                              int4* __restrict__ whf,
                                              float2* __restrict__ eap,
                                              float2* __restrict__ ebp) {
    __shared__ float xl[8 * FDIM];
    int t = threadIdx.x;

    if (blockIdx.x < 16384) {
        // ---------------- adj bitmask part ----------------
        int g = blockIdx.x * 256 + t;               // [0, B*N*64*8)
        int l = g & 7;                              // lane within 8-group
        int word = g >> 3;                          // [0, B*N*64)
        int wk = word & 63;
        int row = word >> 6;                        // b*N + i
        int i = row & (NSZ - 1);
        const float4 v = *(const float4*)&adj[(size_t)row * NSZ + wk * 32 + l * 4];
        unsigned m = 0;
        if (v.x > 0.f) m |= 1u << (l * 4 + 0);
        if (v.y > 0.f) m |= 1u << (l * 4 + 1);
        if (v.z > 0.f) m |= 1u << (l * 4 + 2);
        if (v.w > 0.f) m |= 1u << (l * 4 + 3);
        m |= (unsigned)__shfl_xor((int)m, 1);
        m |= (unsigned)__shfl_xor((int)m, 2);
        m |= (unsigned)__shfl_xor((int)m, 4);
        if (l == 0) {
            int jb = i - wk * 32;
            if (jb >= 0 && jb < 32) m |= 1u << jb;  // self-loop
            adjb[word] = m;
        }
        return;
    }

    // ---------------- Wh projection part ----------------
    int bidx = blockIdx.x - 16384;
    int b = bidx >> 8;
    int n0 = (bidx & 255) * 8;
    // stage 8 x-rows (1024 floats) coalesced
    ((float4*)xl)[t] = ((const float4*)(x + (size_t)(b * NSZ + n0) * FDIM))[t];
    __syncthreads();

    int h = t >> 5, o = t & 31;
    float acc[8];
#pragma unroll
    for (int nn = 0; nn < 8; nn++) acc[nn] = 0.f;

    const float* wp = W + (size_t)h * FDIM * ODIM + o;
#pragma unroll 4
    for (int f = 0; f < FDIM; f += 4) {
        float w0 = wp[(f + 0) * ODIM];
        float w1 = wp[(f + 1) * ODIM];
        float w2 = wp[(f + 2) * ODIM];
        float w3 = wp[(f + 3) * ODIM];
#pragma unroll
        for (int nn = 0; nn < 8; nn++) {
            float4 xv = *(const float4*)&xl[nn * FDIM + f];
            acc[nn] += xv.x * w0 + xv.y * w1 + xv.z * w2 + xv.w * w3;
        }
    }

    float as = a_src[h * ODIM + o];
    float ad = a_dst[h * ODIM + o];
#pragma unroll
    for (int nn = 0; nn < 8; nn++) {
        float vs = acc[nn] * as;
        float vd = acc[nn] * ad;
#pragma unroll
        for (int mk = 16; mk; mk >>= 1) {
            vs += __shfl_xor(vs, mk);
            vd += __shfl_xor(vd, mk);
        }
        if (o == 0) {
            // separable exp factors: p = max(EA_i*EB_j, EA2_i*EB2_j) = exp(lrelu(s)-16)
            size_t idx = (size_t)(b * HH + h) * NSZ + n0 + nn;
            eap[idx] = make_float2(__expf(vs - 8.f), __expf(0.2f * vs - 8.f));
            ebp[idx] = make_float2(__expf(vd - 8.f), __expf(0.2f * vd - 8.f));
        }
    }

    // pack 8 bf16 (element j = acc[j]) and store one 16B fragment chunk
    int jt = n0 >> 5;
    int quad = (n0 >> 3) & 3;
    int ot = o >> 4;
    int lane = quad * 16 + (o & 15);
    unsigned d0 = (bfbits(acc[0]) >> 16) | (bfbits(acc[1]) & 0xffff0000u);
    unsigned d1 = (bfbits(acc[2]) >> 16) | (bfbits(acc[3]) & 0xffff0000u);
    unsigned d2 = (bfbits(acc[4]) >> 16) | (bfbits(acc[5]) & 0xffff0000u);
    unsigned d3 = (bfbits(acc[6]) >> 16) | (bfbits(acc[7]) & 0xffff0000u);
    whf[(((size_t)(b * HH + h) * 64 + jt) * 2 + ot) * 64 + lane] =
        make_int4((int)d0, (int)d1, (int)d2, (int)d3);
}

// ---------------------------------------------------------------------------
// Kernel 2: fused masked-softmax aggregation via MFMA.
// j-SPLIT x2: one (b,h,16-row i-tile) unit = 2 waves, each covering 32 of the
// 64 j-tiles; partners combine acc0/acc1/accd through LDS at the end.
// Grid 2048 blocks -> 8192 waves -> 32 waves/CU (VGPR<=64 via launch_bounds).
// p = max(EA_i*EB_j, EA2_i*EB2_j) masked, bf16-packed; den via ones-B MFMA.
// ---------------------------------------------------------------------------
__global__ __launch_bounds__(256, 8) void k_gat(const int4* __restrict__ whf,
                                                const float2* __restrict__ eap,
                                                const float2* __restrict__ ebp,
                                                const unsigned* __restrict__ adjb,
                                                float* __restrict__ out) {
    __shared__ float comb[2][12][64];

    int t = threadIdx.x;
    int wave = t >> 6;
    int lane = t & 63;
    int pu = wave >> 1;                              // unit within block (0/1)
    int jh = wave & 1;                               // j-half
    int unit = blockIdx.x * 2 + pu;                  // [0, 4096)
    int i0 = (unit & 127) << 4;
    int h = (unit >> 7) & 7;
    int b = unit >> 10;
    int col = lane & 15;
    int quad = lane >> 4;
    int qsh = quad * 8;

    float2 ea = eap[(size_t)(b * HH + h) * NSZ + i0 + col];  // (EA, EA2) for row i
    const float4* eb4 = (const float4*)(ebp + (size_t)(b * HH + h) * NSZ + qsh);
    const uint4* abp4 = (const uint4*)(adjb + ((size_t)(b * NSZ) + i0 + col) * 64 + jh * 32);
    const int4* bfp = whf + (size_t)(b * HH + h) * 8192 + lane;

    f32x4 acc0 = {0.f, 0.f, 0.f, 0.f};
    f32x4 acc1 = {0.f, 0.f, 0.f, 0.f};
    f32x4 accd = {0.f, 0.f, 0.f, 0.f};
    const int4 onesv = make_int4(0x3F803F80, 0x3F803F80, 0x3F803F80, 0x3F803F80);
    short8 bones = __builtin_bit_cast(short8, onesv);
    float eaa = ea.x, eab = ea.y;

    for (int jt4 = 0; jt4 < 8; jt4++) {
        uint4 mw = abp4[jt4];                        // 4 jt's mask words at once
        unsigned mwa[4] = {mw.x, mw.y, mw.z, mw.w};
#pragma unroll
        for (int q = 0; q < 4; q++) {
            int jt = jh * 32 + jt4 * 4 + q;
            unsigned w = mwa[q] >> qsh;              // 8 mask bits for this lane
            float4 l0 = eb4[jt * 16 + 0];
            float4 l1 = eb4[jt * 16 + 1];
            float4 l2 = eb4[jt * 16 + 2];
            float4 l3 = eb4[jt * 16 + 3];
            int4 blo = bfp[jt * 128];                // B-frag, o 0..15
            int4 bhi = bfp[jt * 128 + 64];           // B-frag, o 16..31
            float p0, p1, p2, p3, p4, p5, p6, p7;
            p0 = fmaxf(eaa * l0.x, eab * l0.y);
            p1 = fmaxf(eaa * l0.z, eab * l0.w);
            p2 = fmaxf(eaa * l1.x, eab * l1.y);
            p3 = fmaxf(eaa * l1.z, eab * l1.w);
            p4 = fmaxf(eaa * l2.x, eab * l2.y);
            p5 = fmaxf(eaa * l2.z, eab * l2.w);
            p6 = fmaxf(eaa * l3.x, eab * l3.y);
            p7 = fmaxf(eaa * l3.z, eab * l3.w);
            p0 = (w & 1u)   ? p0 : 0.f;
            p1 = (w & 2u)   ? p1 : 0.f;
            p2 = (w & 4u)   ? p2 : 0.f;
            p3 = (w & 8u)   ? p3 : 0.f;
            p4 = (w & 16u)  ? p4 : 0.f;
            p5 = (w & 32u)  ? p5 : 0.f;
            p6 = (w & 64u)  ? p6 : 0.f;
            p7 = (w & 128u) ? p7 : 0.f;
            // round-half-up + byte-perm pack: dword = (odd_hi16 << 16) | even_hi16
            unsigned u0 = __builtin_bit_cast(unsigned, p0) + 0x8000u;
            unsigned u1 = __builtin_bit_cast(unsigned, p1) + 0x8000u;
            unsigned u2 = __builtin_bit_cast(unsigned, p2) + 0x8000u;
            unsigned u3 = __builtin_bit_cast(unsigned, p3) + 0x8000u;
            unsigned u4 = __builtin_bit_cast(unsigned, p4) + 0x8000u;
            unsigned u5 = __builtin_bit_cast(unsigned, p5) + 0x8000u;
            unsigned u6 = __builtin_bit_cast(unsigned, p6) + 0x8000u;
            unsigned u7 = __builtin_bit_cast(unsigned, p7) + 0x8000u;
            int4 aw = make_int4((int)__builtin_amdgcn_perm(u1, u0, 0x07060302),
                                (int)__builtin_amdgcn_perm(u3, u2, 0x07060302),
                                (int)__builtin_amdgcn_perm(u5, u4, 0x07060302),
                                (int)__builtin_amdgcn_perm(u7, u6, 0x07060302));
            short8 afr = __builtin_bit_cast(short8, aw);
            acc0 = __builtin_amdgcn_mfma_f32_16x16x32_bf16(afr, __builtin_bit_cast(short8, blo), acc0, 0, 0, 0);
            acc1 = __builtin_amdgcn_mfma_f32_16x16x32_bf16(afr, __builtin_bit_cast(short8, bhi), acc1, 0, 0, 0);
            accd = __builtin_amdgcn_mfma_f32_16x16x32_bf16(afr, bones, accd, 0, 0, 0);
        }
    }

    // ---- combine j-halves through LDS ----
    if (jh) {
#pragma unroll
        for (int r = 0; r < 4; r++) {
            comb[pu][r][lane]     = acc0[r];
            comb[pu][4 + r][lane] = acc1[r];
            comb[pu][8 + r][lane] = accd[r];
        }
    }
    __syncthreads();
    if (jh) return;
#pragma unroll
    for (int r = 0; r < 4; r++) {
        acc0[r] += comb[pu][r][lane];
        acc1[r] += comb[pu][4 + r][lane];
        accd[r] += comb[pu][8 + r][lane];
    }

    // C/D layout: col = lane&15, row = quad*4 + reg; accd[r] = row-sum = den
    float* op = out + ((size_t)(b * NSZ) + i0) * (HH * ODIM) + h * ODIM + col;
#pragma unroll
    for (int r = 0; r < 4; r++) {
        int row = quad * 4 + r;
        float inv = 1.0f / accd[r];
        op[(size_t)row * (HH * ODIM)] = fmaxf(acc0[r] * inv, 0.f);
        op[(size_t)row * (HH * ODIM) + 16] = fmaxf(acc1[r] * inv, 0.f);
    }
}

extern "C" void kernel_launch(void* const* d_in, const int* in_sizes, int n_in,
                              void* d_out, int out_size, void* d_ws, size_t ws_size,
                              hipStream_t stream) {
    const float* x     = (const float*)d_in[0];
    const float* adj   = (const float*)d_in[1];
    const float* W     = (const float*)d_in[2];
    const float* a_src = (const float*)d_in[3];
    const float* a_dst = (const float*)d_in[4];
    float* out = (float*)d_out;

    float* ws = (float*)d_ws;
    float2* eap    = (float2*)(ws + WS_EAP);
    float2* ebp    = (float2*)(ws + WS_EBP);
    unsigned* adjb = (unsigned*)(ws + WS_ADJB);
    int4* whf      = (int4*)(ws + WS_WHF);

    // fused prep: 16384 adj-bitmask blocks first (HBM stream), then 1024 wh blocks
    k_prep<<<dim3(16384 + 1024), dim3(256), 0, stream>>>(x, adj, W, a_src, a_dst,
                                                         adjb, whf, eap, ebp);
    // fused masked softmax + MFMA aggregation: j-split x2, 8192 waves
    k_gat<<<dim3(BB * HH * (NSZ / 16) / 2), dim3(256), 0, stream>>>(whf, eap, ebp, adjb, out);
}

// Round 5
// 147.454 us; speedup vs baseline: 1.2843x; 1.2843x over previous
//
#include <hip/hip_runtime.h>
#include <math.h>

#define BB 4
#define NSZ 2048
#define FDIM 128
#define ODIM 32
#define HH 8

typedef short short8 __attribute__((ext_vector_type(8)));
typedef float f32x4 __attribute__((ext_vector_type(4)));

// workspace layout (float units)
#define WS_EAP  0                 // float2[B*H*N] (EA, EA2)   = 131072 floats
#define WS_EBP  131072            // float2[B*H*N] (EB, EB2)   = 131072 floats
#define WS_ADJB 262144            // u32[B*N*64]               = 524288 words
#define WS_WHF  786432            // bf16 Wh B-frags           = 1048576 floats (4MB)
#define WS_WF   1835008           // bf16 W  B-frags           = 8192 floats (32KB)
// whf: int4[((b*H+h)*64 + jt)*2 + ot][64 lanes]; wf: int4[(h*4+kt)*2+ot][64]

// round-to-nearest-even float -> bf16, result in TOP 16 bits
__device__ __forceinline__ unsigned bfbits(float f) {
    unsigned u = __builtin_bit_cast(unsigned, f);
    return u + 0x7fffu + ((u >> 16) & 1u);
}
// dword = (bf16(b) << 16) | bf16(a)
__device__ __forceinline__ unsigned bfpack(float a, float b) {
    return __builtin_amdgcn_perm(bfbits(b), bfbits(a), 0x07060302);
}

// ---------------------------------------------------------------------------
// Pack W[h] into bf16 MFMA B-fragments (runs once per call; 8 tiny blocks).
// frag(kt,ot): element j of lane(quad,col) = W[h][kt*32+quad*8+j][ot*16+col].
// ---------------------------------------------------------------------------
__global__ __launch_bounds__(256) void k_wpack(const float* __restrict__ W,
                                               int4* __restrict__ wf) {
    int h = blockIdx.x;
    int t = threadIdx.x;
    int kt = t >> 6, lane = t & 63;
    int col = lane & 15, quad = lane >> 4;
    const float* wp = W + ((size_t)h * FDIM + kt * 32 + quad * 8) * ODIM;
#pragma unroll
    for (int ot = 0; ot < 2; ot++) {
        unsigned d[4];
#pragma unroll
        for (int jp = 0; jp < 4; jp++) {
            float lo = wp[(2 * jp) * ODIM + ot * 16 + col];
            float hi = wp[(2 * jp + 1) * ODIM + ot * 16 + col];
            d[jp] = bfpack(lo, hi);
        }
        wf[((h * 4 + kt) * 2 + ot) * 64 + lane] =
            make_int4((int)d[0], (int)d[1], (int)d[2], (int)d[3]);
    }
}

// ---------------------------------------------------------------------------
// Fused prep. Blocks [0,16384): adj bitmask pack (HBM stream).
// Blocks [16384,17408): MFMA projection for one (b,h,64 n-rows):
//   Wh tile via mfma(x_bf16, W_frag), alphas from C-layout + shuffles,
//   exp factors stored, Wh re-packed to B-frags via LDS transpose.
// ---------------------------------------------------------------------------
__global__ __launch_bounds__(256) void k_prep(const float* __restrict__ x,
                                              const float* __restrict__ adj,
                                              const float* __restrict__ a_src,
                                              const float* __restrict__ a_dst,
                                              const int4* __restrict__ wf,
                                              unsigned* __restrict__ adjb,
                                              int4* __restrict__ whf,
                                              float2* __restrict__ eap,
                                              float2* __restrict__ ebp) {
    __shared__ unsigned short wlds[64][33];   // bf16 Wh tile [local n][o], +1 pad
    int t = threadIdx.x;

    if (blockIdx.x < 16384) {
        // ---------------- adj bitmask part ----------------
        int g = blockIdx.x * 256 + t;
        int l = g & 7;
        int word = g >> 3;
        int wk = word & 63;
        int row = word >> 6;
        int i = row & (NSZ - 1);
        const float4 v = *(const float4*)&adj[(size_t)row * NSZ + wk * 32 + l * 4];
        unsigned m = 0;
        if (v.x > 0.f) m |= 1u << (l * 4 + 0);
        if (v.y > 0.f) m |= 1u << (l * 4 + 1);
        if (v.z > 0.f) m |= 1u << (l * 4 + 2);
        if (v.w > 0.f) m |= 1u << (l * 4 + 3);
        m |= (unsigned)__shfl_xor((int)m, 1);
        m |= (unsigned)__shfl_xor((int)m, 2);
        m |= (unsigned)__shfl_xor((int)m, 4);
        if (l == 0) {
            int jb = i - wk * 32;
            if (jb >= 0 && jb < 32) m |= 1u << jb;  // self-loop
            adjb[word] = m;
        }
        return;
    }

    // ---------------- projection part ----------------
    int bidx = blockIdx.x - 16384;              // [0,1024): b(2) h(3) nt(5)
    int b = bidx >> 8;
    int h = (bidx >> 5) & 7;
    int nt = bidx & 31;
    int n0 = nt * 64;
    int w = t >> 6, lane = t & 63;
    int col = lane & 15, quad = lane >> 4;

    // A-fragments: lane(quad,col) element j = x[b][n0+w*16+col][kt*32+quad*8+j]
    const float* xp = x + ((size_t)(b * NSZ) + n0 + w * 16 + col) * FDIM + quad * 8;
    int4 afr[4];
#pragma unroll
    for (int kt = 0; kt < 4; kt++) {
        float4 xa = *(const float4*)(xp + kt * 32);
        float4 xb = *(const float4*)(xp + kt * 32 + 4);
        afr[kt] = make_int4((int)bfpack(xa.x, xa.y), (int)bfpack(xa.z, xa.w),
                            (int)bfpack(xb.x, xb.y), (int)bfpack(xb.z, xb.w));
    }

    // W fragments + 8 MFMA: acc rows = quad*4+r (local), cols = col (+16)
    const int4* wfp = wf + h * 8 * 64 + lane;
    f32x4 alo = {0.f, 0.f, 0.f, 0.f};
    f32x4 ahi = {0.f, 0.f, 0.f, 0.f};
#pragma unroll
    for (int kt = 0; kt < 4; kt++) {
        short8 a8 = __builtin_bit_cast(short8, afr[kt]);
        alo = __builtin_amdgcn_mfma_f32_16x16x32_bf16(a8,
                __builtin_bit_cast(short8, wfp[(kt * 2 + 0) * 64]), alo, 0, 0, 0);
        ahi = __builtin_amdgcn_mfma_f32_16x16x32_bf16(a8,
                __builtin_bit_cast(short8, wfp[(kt * 2 + 1) * 64]), ahi, 0, 0, 0);
    }

    // alphas: reduce Wh[row]*a over o (col lanes), then exp factors
    float as0 = a_src[h * ODIM + col], as1 = a_src[h * ODIM + 16 + col];
    float ad0 = a_dst[h * ODIM + col], ad1 = a_dst[h * ODIM + 16 + col];
#pragma unroll
    for (int r = 0; r < 4; r++) {
        float pa = alo[r] * as0 + ahi[r] * as1;
        float pb = alo[r] * ad0 + ahi[r] * ad1;
#pragma unroll
        for (int mk = 1; mk <= 8; mk <<= 1) {
            pa += __shfl_xor(pa, mk);
            pb += __shfl_xor(pb, mk);
        }
        if (col == 0) {
            size_t idx = (size_t)(b * HH + h) * NSZ + n0 + w * 16 + quad * 4 + r;
            eap[idx] = make_float2(__expf(pa - 8.f), __expf(0.2f * pa - 8.f));
            ebp[idx] = make_float2(__expf(pb - 8.f), __expf(0.2f * pb - 8.f));
        }
    }

    // Wh -> LDS (bf16), then gather B-fragments: wave w does (jl=w>>1, ot=w&1)
#pragma unroll
    for (int r = 0; r < 4; r++) {
        wlds[w * 16 + quad * 4 + r][col]      = (unsigned short)(bfbits(alo[r]) >> 16);
        wlds[w * 16 + quad * 4 + r][col + 16] = (unsigned short)(bfbits(ahi[r]) >> 16);
    }
    __syncthreads();
    int jl = w >> 1, ot = w & 1;
    unsigned d[4];
#pragma unroll
    for (int jp = 0; jp < 4; jp++) {
        unsigned lo = wlds[jl * 32 + quad * 8 + 2 * jp][ot * 16 + col];
        unsigned hi = wlds[jl * 32 + quad * 8 + 2 * jp + 1][ot * 16 + col];
        d[jp] = (hi << 16) | lo;
    }
    int fragid = ((b * HH + h) * 64 + nt * 2 + jl) * 2 + ot;
    whf[(size_t)fragid * 64 + lane] = make_int4((int)d[0], (int)d[1], (int)d[2], (int)d[3]);
}

// masked p-fragment: 8 j's -> bf16x8 A-frag (round-half-up + perm pack)
__device__ __forceinline__ int4 pfrag(float eaa, float eab, const float4& l0,
                                      const float4& l1, const float4& l2,
                                      const float4& l3, unsigned w) {
    float p0 = fmaxf(eaa * l0.x, eab * l0.y);
    float p1 = fmaxf(eaa * l0.z, eab * l0.w);
    float p2 = fmaxf(eaa * l1.x, eab * l1.y);
    float p3 = fmaxf(eaa * l1.z, eab * l1.w);
    float p4 = fmaxf(eaa * l2.x, eab * l2.y);
    float p5 = fmaxf(eaa * l2.z, eab * l2.w);
    float p6 = fmaxf(eaa * l3.x, eab * l3.y);
    float p7 = fmaxf(eaa * l3.z, eab * l3.w);
    p0 = (w & 1u)   ? p0 : 0.f;
    p1 = (w & 2u)   ? p1 : 0.f;
    p2 = (w & 4u)   ? p2 : 0.f;
    p3 = (w & 8u)   ? p3 : 0.f;
    p4 = (w & 16u)  ? p4 : 0.f;
    p5 = (w & 32u)  ? p5 : 0.f;
    p6 = (w & 64u)  ? p6 : 0.f;
    p7 = (w & 128u) ? p7 : 0.f;
    unsigned u0 = __builtin_bit_cast(unsigned, p0) + 0x8000u;
    unsigned u1 = __builtin_bit_cast(unsigned, p1) + 0x8000u;
    unsigned u2 = __builtin_bit_cast(unsigned, p2) + 0x8000u;
    unsigned u3 = __builtin_bit_cast(unsigned, p3) + 0x8000u;
    unsigned u4 = __builtin_bit_cast(unsigned, p4) + 0x8000u;
    unsigned u5 = __builtin_bit_cast(unsigned, p5) + 0x8000u;
    unsigned u6 = __builtin_bit_cast(unsigned, p6) + 0x8000u;
    unsigned u7 = __builtin_bit_cast(unsigned, p7) + 0x8000u;
    return make_int4((int)__builtin_amdgcn_perm(u1, u0, 0x07060302),
                     (int)__builtin_amdgcn_perm(u3, u2, 0x07060302),
                     (int)__builtin_amdgcn_perm(u5, u4, 0x07060302),
                     (int)__builtin_amdgcn_perm(u7, u6, 0x07060302));
}

// ---------------------------------------------------------------------------
// Fused masked-softmax aggregation. Block = (b,h,64 i-rows), 4 waves =
// 2 it (32 rows each) x 2 jh (j-halves). ebp staged once in LDS (16KB);
// each whf B-frag load feeds 2 i-tiles (6 MFMA). LDS combine of j-halves.
// ---------------------------------------------------------------------------
__global__ __launch_bounds__(256) void k_gat(const int4* __restrict__ whf,
                                             const float2* __restrict__ eap,
                                             const float2* __restrict__ ebp,
                                             const unsigned* __restrict__ adjb,
                                             float* __restrict__ out) {
    __shared__ float ebl[4096];          // (EB,EB2)[2048] for this (b,h)
    __shared__ float comb[2][24][64];    // j-half combine

    int t = threadIdx.x;
    int u = blockIdx.x;
    int unit = (u & 7) * 128 + (u >> 3);  // XCD swizzle: each XCD sees 4 (b,h)
    int b = unit >> 8;
    int h = (unit >> 5) & 7;
    int i0 = (unit & 31) * 64;
    int wave = t >> 6, lane = t & 63;
    int it = wave & 1, jh = wave >> 1;
    int col = lane & 15, quad = lane >> 4, qsh = quad * 8;
    size_t bh = (size_t)(b * HH + h);

    // stage eb table: 4096 floats, coalesced
    const float4* ebg = (const float4*)(ebp + bh * NSZ);
#pragma unroll
    for (int k = 0; k < 4; k++) ((float4*)ebl)[t + k * 256] = ebg[t + k * 256];

    int iw = i0 + it * 32;
    float2 ea0 = eap[bh * NSZ + iw + col];
    float2 ea1 = eap[bh * NSZ + iw + 16 + col];
    const uint4* mp0 = (const uint4*)(adjb + ((size_t)(b * NSZ) + iw + col) * 64) + jh * 8;
    const uint4* mp1 = (const uint4*)(adjb + ((size_t)(b * NSZ) + iw + 16 + col) * 64) + jh * 8;
    const int4* bfp = whf + bh * 8192 + lane;

    f32x4 a00 = {0.f,0.f,0.f,0.f}, a01 = {0.f,0.f,0.f,0.f}, a0d = {0.f,0.f,0.f,0.f};
    f32x4 a10 = {0.f,0.f,0.f,0.f}, a11 = {0.f,0.f,0.f,0.f}, a1d = {0.f,0.f,0.f,0.f};
    const int4 onesv = make_int4(0x3F803F80, 0x3F803F80, 0x3F803F80, 0x3F803F80);
    short8 bones = __builtin_bit_cast(short8, onesv);

    __syncthreads();

    for (int jt4 = 0; jt4 < 8; jt4++) {
        uint4 m0 = mp0[jt4];
        uint4 m1 = mp1[jt4];
        unsigned m0a[4] = {m0.x, m0.y, m0.z, m0.w};
        unsigned m1a[4] = {m1.x, m1.y, m1.z, m1.w};
#pragma unroll
        for (int q = 0; q < 4; q++) {
            int jt = jh * 32 + jt4 * 4 + q;
            const float4* el = (const float4*)&ebl[(jt * 32 + qsh) * 2];
            float4 l0 = el[0], l1 = el[1], l2 = el[2], l3 = el[3];
            int4 blo = bfp[jt * 128];
            int4 bhi = bfp[jt * 128 + 64];
            int4 f0 = pfrag(ea0.x, ea0.y, l0, l1, l2, l3, m0a[q] >> qsh);
            int4 f1 = pfrag(ea1.x, ea1.y, l0, l1, l2, l3, m1a[q] >> qsh);
            short8 af0 = __builtin_bit_cast(short8, f0);
            short8 af1 = __builtin_bit_cast(short8, f1);
            short8 b0 = __builtin_bit_cast(short8, blo);
            short8 b1 = __builtin_bit_cast(short8, bhi);
            a00 = __builtin_amdgcn_mfma_f32_16x16x32_bf16(af0, b0, a00, 0, 0, 0);
            a01 = __builtin_amdgcn_mfma_f32_16x16x32_bf16(af0, b1, a01, 0, 0, 0);
            a0d = __builtin_amdgcn_mfma_f32_16x16x32_bf16(af0, bones, a0d, 0, 0, 0);
            a10 = __builtin_amdgcn_mfma_f32_16x16x32_bf16(af1, b0, a10, 0, 0, 0);
            a11 = __builtin_amdgcn_mfma_f32_16x16x32_bf16(af1, b1, a11, 0, 0, 0);
            a1d = __builtin_amdgcn_mfma_f32_16x16x32_bf16(af1, bones, a1d, 0, 0, 0);
        }
    }

    // combine j-halves through LDS
    if (jh) {
#pragma unroll
        for (int r = 0; r < 4; r++) {
            comb[it][r][lane]      = a00[r];
            comb[it][4 + r][lane]  = a01[r];
            comb[it][8 + r][lane]  = a0d[r];
            comb[it][12 + r][lane] = a10[r];
            comb[it][16 + r][lane] = a11[r];
            comb[it][20 + r][lane] = a1d[r];
        }
    }
    __syncthreads();
    if (jh) return;
#pragma unroll
    for (int r = 0; r < 4; r++) {
        a00[r] += comb[it][r][lane];
        a01[r] += comb[it][4 + r][lane];
        a0d[r] += comb[it][8 + r][lane];
        a10[r] += comb[it][12 + r][lane];
        a11[r] += comb[it][16 + r][lane];
        a1d[r] += comb[it][20 + r][lane];
    }

    // epilogue: C/D layout col=lane&15, row=quad*4+reg; a*d[r] = row denominator
    float* op = out + ((size_t)(b * NSZ) + iw) * (HH * ODIM) + h * ODIM + col;
#pragma unroll
    for (int r = 0; r < 4; r++) {
        int row = quad * 4 + r;
        float inv0 = 1.0f / a0d[r];
        float inv1 = 1.0f / a1d[r];
        op[(size_t)row * (HH * ODIM)]           = fmaxf(a00[r] * inv0, 0.f);
        op[(size_t)row * (HH * ODIM) + 16]      = fmaxf(a01[r] * inv0, 0.f);
        op[(size_t)(row + 16) * (HH * ODIM)]      = fmaxf(a10[r] * inv1, 0.f);
        op[(size_t)(row + 16) * (HH * ODIM) + 16] = fmaxf(a11[r] * inv1, 0.f);
    }
}

extern "C" void kernel_launch(void* const* d_in, const int* in_sizes, int n_in,
                              void* d_out, int out_size, void* d_ws, size_t ws_size,
                              hipStream_t stream) {
    const float* x     = (const float*)d_in[0];
    const float* adj   = (const float*)d_in[1];
    const float* W     = (const float*)d_in[2];
    const float* a_src = (const float*)d_in[3];
    const float* a_dst = (const float*)d_in[4];
    float* out = (float*)d_out;

    float* ws = (float*)d_ws;
    float2* eap    = (float2*)(ws + WS_EAP);
    float2* ebp    = (float2*)(ws + WS_EBP);
    unsigned* adjb = (unsigned*)(ws + WS_ADJB);
    int4* whf      = (int4*)(ws + WS_WHF);
    int4* wfr      = (int4*)(ws + WS_WF);

    // pack W into bf16 B-fragments (tiny)
    k_wpack<<<dim3(HH), dim3(256), 0, stream>>>(W, wfr);
    // fused prep: 16384 adj-bitmask blocks + 1024 MFMA-projection blocks
    k_prep<<<dim3(16384 + 1024), dim3(256), 0, stream>>>(x, adj, a_src, a_dst, wfr,
                                                         adjb, whf, eap, ebp);
    // fused masked softmax + MFMA aggregation: 1024 blocks x 4 waves
    k_gat<<<dim3(BB * HH * (NSZ / 64)), dim3(256), 0, stream>>>(whf, eap, ebp, adjb, out);
}

// Round 6
// 136.462 us; speedup vs baseline: 1.3878x; 1.0806x over previous
//
#include <hip/hip_runtime.h>
#include <math.h>

#define BB 4
#define NSZ 2048
#define FDIM 128
#define ODIM 32
#define HH 8

typedef short short8 __attribute__((ext_vector_type(8)));
typedef float f32x4 __attribute__((ext_vector_type(4)));

// workspace layout (float units)
#define WS_EAP  0                 // float2[B*H*N] (EA, EA2)   = 131072 floats
#define WS_EBP  131072            // float2[B*H*N] (EB, EB2)   = 131072 floats
#define WS_ADJB 262144            // u32[B*N*64]               = 524288 words
#define WS_WHF  786432            // bf16 Wh B-frags           = 1048576 floats (4MB)
// whf: int4[((b*H+h)*64 + jt)*2 + ot][64 lanes]

// round-to-nearest-even float -> bf16, result in TOP 16 bits
__device__ __forceinline__ unsigned bfbits(float f) {
    unsigned u = __builtin_bit_cast(unsigned, f);
    return u + 0x7fffu + ((u >> 16) & 1u);
}
// dword = (bf16(b) << 16) | bf16(a)
__device__ __forceinline__ unsigned bfpack(float a, float b) {
    return __builtin_amdgcn_perm(bfbits(b), bfbits(a), 0x07060302);
}

// ---------------------------------------------------------------------------
// Fused prep. Blocks [0,16384): adj bitmask pack (HBM stream).
// Blocks [16384,17408): MFMA projection for one (b,h,64 n-rows). W[h] is
// staged per-block into padded LDS and B-frags built in-block (k_wpack gone).
// ---------------------------------------------------------------------------
__global__ __launch_bounds__(256) void k_prep(const float* __restrict__ x,
                                              const float* __restrict__ adj,
                                              const float* __restrict__ W,
                                              const float* __restrict__ a_src,
                                              const float* __restrict__ a_dst,
                                              unsigned* __restrict__ adjb,
                                              int4* __restrict__ whf,
                                              float2* __restrict__ eap,
                                              float2* __restrict__ ebp) {
    __shared__ float wsl[FDIM * 33];          // W[h] staged, row-padded (k*33+o)
    __shared__ unsigned short wlds[64][33];   // bf16 Wh tile [local n][o], +1 pad
    int t = threadIdx.x;

    if (blockIdx.x < 16384) {
        // ---------------- adj bitmask part ----------------
        int g = blockIdx.x * 256 + t;
        int l = g & 7;
        int word = g >> 3;
        int wk = word & 63;
        int row = word >> 6;
        int i = row & (NSZ - 1);
        const float4 v = *(const float4*)&adj[(size_t)row * NSZ + wk * 32 + l * 4];
        unsigned m = 0;
        if (v.x > 0.f) m |= 1u << (l * 4 + 0);
        if (v.y > 0.f) m |= 1u << (l * 4 + 1);
        if (v.z > 0.f) m |= 1u << (l * 4 + 2);
        if (v.w > 0.f) m |= 1u << (l * 4 + 3);
        m |= (unsigned)__shfl_xor((int)m, 1);
        m |= (unsigned)__shfl_xor((int)m, 2);
        m |= (unsigned)__shfl_xor((int)m, 4);
        if (l == 0) {
            int jb = i - wk * 32;
            if (jb >= 0 && jb < 32) m |= 1u << jb;  // self-loop
            adjb[word] = m;
        }
        return;
    }

    // ---------------- projection part ----------------
    int bidx = blockIdx.x - 16384;              // [0,1024): b(2) h(3) nt(5)
    int b = bidx >> 8;
    int h = (bidx >> 5) & 7;
    int nt = bidx & 31;
    int n0 = nt * 64;
    int w = t >> 6, lane = t & 63;
    int col = lane & 15, quad = lane >> 4;

    // stage W[h] (4096 floats) coalesced into padded LDS
#pragma unroll
    for (int m = 0; m < 16; m++) {
        int idx = t + m * 256;
        wsl[(idx >> 5) * 33 + (idx & 31)] = W[(size_t)h * (FDIM * ODIM) + idx];
    }

    // A-fragments: lane(quad,col) element j = x[b][n0+w*16+col][kt*32+quad*8+j]
    const float* xp = x + ((size_t)(b * NSZ) + n0 + w * 16 + col) * FDIM + quad * 8;
    int4 afr[4];
#pragma unroll
    for (int kt = 0; kt < 4; kt++) {
        float4 xa = *(const float4*)(xp + kt * 32);
        float4 xb = *(const float4*)(xp + kt * 32 + 4);
        afr[kt] = make_int4((int)bfpack(xa.x, xa.y), (int)bfpack(xa.z, xa.w),
                            (int)bfpack(xb.x, xb.y), (int)bfpack(xb.z, xb.w));
    }
    __syncthreads();

    // build W B-frags from LDS and run 8 MFMAs
    f32x4 alo = {0.f, 0.f, 0.f, 0.f};
    f32x4 ahi = {0.f, 0.f, 0.f, 0.f};
#pragma unroll
    for (int kt = 0; kt < 4; kt++) {
        short8 a8 = __builtin_bit_cast(short8, afr[kt]);
#pragma unroll
        for (int ot = 0; ot < 2; ot++) {
            unsigned d[4];
#pragma unroll
            for (int jp = 0; jp < 4; jp++) {
                float lo = wsl[(kt * 32 + quad * 8 + 2 * jp) * 33 + ot * 16 + col];
                float hi = wsl[(kt * 32 + quad * 8 + 2 * jp + 1) * 33 + ot * 16 + col];
                d[jp] = bfpack(lo, hi);
            }
            int4 bf = make_int4((int)d[0], (int)d[1], (int)d[2], (int)d[3]);
            if (ot == 0)
                alo = __builtin_amdgcn_mfma_f32_16x16x32_bf16(a8,
                        __builtin_bit_cast(short8, bf), alo, 0, 0, 0);
            else
                ahi = __builtin_amdgcn_mfma_f32_16x16x32_bf16(a8,
                        __builtin_bit_cast(short8, bf), ahi, 0, 0, 0);
        }
    }

    // alphas: reduce Wh[row]*a over o (col lanes), then exp factors
    float as0 = a_src[h * ODIM + col], as1 = a_src[h * ODIM + 16 + col];
    float ad0 = a_dst[h * ODIM + col], ad1 = a_dst[h * ODIM + 16 + col];
#pragma unroll
    for (int r = 0; r < 4; r++) {
        float pa = alo[r] * as0 + ahi[r] * as1;
        float pb = alo[r] * ad0 + ahi[r] * ad1;
#pragma unroll
        for (int mk = 1; mk <= 8; mk <<= 1) {
            pa += __shfl_xor(pa, mk);
            pb += __shfl_xor(pb, mk);
        }
        if (col == 0) {
            size_t idx = (size_t)(b * HH + h) * NSZ + n0 + w * 16 + quad * 4 + r;
            eap[idx] = make_float2(__expf(pa - 8.f), __expf(0.2f * pa - 8.f));
            ebp[idx] = make_float2(__expf(pb - 8.f), __expf(0.2f * pb - 8.f));
        }
    }

    // Wh -> LDS (bf16), then gather B-fragments: wave w does (jl=w>>1, ot=w&1)
#pragma unroll
    for (int r = 0; r < 4; r++) {
        wlds[w * 16 + quad * 4 + r][col]      = (unsigned short)(bfbits(alo[r]) >> 16);
        wlds[w * 16 + quad * 4 + r][col + 16] = (unsigned short)(bfbits(ahi[r]) >> 16);
    }
    __syncthreads();
    int jl = w >> 1, ot = w & 1;
    unsigned d[4];
#pragma unroll
    for (int jp = 0; jp < 4; jp++) {
        unsigned lo = wlds[jl * 32 + quad * 8 + 2 * jp][ot * 16 + col];
        unsigned hi = wlds[jl * 32 + quad * 8 + 2 * jp + 1][ot * 16 + col];
        d[jp] = (hi << 16) | lo;
    }
    int fragid = ((b * HH + h) * 64 + nt * 2 + jl) * 2 + ot;
    whf[(size_t)fragid * 64 + lane] = make_int4((int)d[0], (int)d[1], (int)d[2], (int)d[3]);
}

// masked p-fragment: 8 j's -> bf16x8 A-frag. Mask applied on PACKED dwords
// via 16-entry LDS LUT (4 mask bits -> 64-bit AND mask): ~0.9 VALU/p vs 3.
__device__ __forceinline__ int4 pfrag(float eaa, float eab, const float4& l0,
                                      const float4& l1, const float4& l2,
                                      const float4& l3, unsigned w,
                                      const unsigned (*__restrict__ mlut)[2]) {
    float p0 = fmaxf(eaa * l0.x, eab * l0.y);
    float p1 = fmaxf(eaa * l0.z, eab * l0.w);
    float p2 = fmaxf(eaa * l1.x, eab * l1.y);
    float p3 = fmaxf(eaa * l1.z, eab * l1.w);
    float p4 = fmaxf(eaa * l2.x, eab * l2.y);
    float p5 = fmaxf(eaa * l2.z, eab * l2.w);
    float p6 = fmaxf(eaa * l3.x, eab * l3.y);
    float p7 = fmaxf(eaa * l3.z, eab * l3.w);
    unsigned u0 = __builtin_bit_cast(unsigned, p0) + 0x8000u;
    unsigned u1 = __builtin_bit_cast(unsigned, p1) + 0x8000u;
    unsigned u2 = __builtin_bit_cast(unsigned, p2) + 0x8000u;
    unsigned u3 = __builtin_bit_cast(unsigned, p3) + 0x8000u;
    unsigned u4 = __builtin_bit_cast(unsigned, p4) + 0x8000u;
    unsigned u5 = __builtin_bit_cast(unsigned, p5) + 0x8000u;
    unsigned u6 = __builtin_bit_cast(unsigned, p6) + 0x8000u;
    unsigned u7 = __builtin_bit_cast(unsigned, p7) + 0x8000u;
    unsigned d0 = __builtin_amdgcn_perm(u1, u0, 0x07060302);
    unsigned d1 = __builtin_amdgcn_perm(u3, u2, 0x07060302);
    unsigned d2 = __builtin_amdgcn_perm(u5, u4, 0x07060302);
    unsigned d3 = __builtin_amdgcn_perm(u7, u6, 0x07060302);
    const unsigned* mA = mlut[w & 15];         // bits 0..3 -> masks for dw0,dw1
    const unsigned* mB = mlut[(w >> 4) & 15];  // bits 4..7 -> masks for dw2,dw3
    return make_int4((int)(d0 & mA[0]), (int)(d1 & mA[1]),
                     (int)(d2 & mB[0]), (int)(d3 & mB[1]));
}

// ---------------------------------------------------------------------------
// Fused masked-softmax aggregation. Block = (b,h,64 i-rows), 4 waves =
// 2 it (32 rows each) x 2 jh (j-halves). ebp staged once in LDS (16KB);
// each whf B-frag load feeds 2 i-tiles (6 MFMA). LDS combine of j-halves.
// ---------------------------------------------------------------------------
__global__ __launch_bounds__(256) void k_gat(const int4* __restrict__ whf,
                                             const float2* __restrict__ eap,
                                             const float2* __restrict__ ebp,
                                             const unsigned* __restrict__ adjb,
                                             float* __restrict__ out) {
    __shared__ float ebl[4096];          // (EB,EB2)[2048] for this (b,h)
    __shared__ float comb[2][24][64];    // j-half combine
    __shared__ unsigned mlut[16][2];     // 4 mask bits -> 2 dword AND-masks

    int t = threadIdx.x;
    int u = blockIdx.x;
    int unit = (u & 7) * 128 + (u >> 3);  // XCD swizzle: each XCD sees 4 (b,h)
    int b = unit >> 8;
    int h = (unit >> 5) & 7;
    int i0 = (unit & 31) * 64;
    int wave = t >> 6, lane = t & 63;
    int it = wave & 1, jh = wave >> 1;
    int col = lane & 15, quad = lane >> 4, qsh = quad * 8;
    size_t bh = (size_t)(b * HH + h);

    if (t < 16) {
        mlut[t][0] = ((t & 1) ? 0x0000FFFFu : 0u) | ((t & 2) ? 0xFFFF0000u : 0u);
        mlut[t][1] = ((t & 4) ? 0x0000FFFFu : 0u) | ((t & 8) ? 0xFFFF0000u : 0u);
    }

    // stage eb table: 4096 floats, coalesced
    const float4* ebg = (const float4*)(ebp + bh * NSZ);
#pragma unroll
    for (int k = 0; k < 4; k++) ((float4*)ebl)[t + k * 256] = ebg[t + k * 256];

    int iw = i0 + it * 32;
    float2 ea0 = eap[bh * NSZ + iw + col];
    float2 ea1 = eap[bh * NSZ + iw + 16 + col];
    const uint4* mp0 = (const uint4*)(adjb + ((size_t)(b * NSZ) + iw + col) * 64) + jh * 8;
    const uint4* mp1 = (const uint4*)(adjb + ((size_t)(b * NSZ) + iw + 16 + col) * 64) + jh * 8;
    const int4* bfp = whf + bh * 8192 + lane;

    f32x4 a00 = {0.f,0.f,0.f,0.f}, a01 = {0.f,0.f,0.f,0.f}, a0d = {0.f,0.f,0.f,0.f};
    f32x4 a10 = {0.f,0.f,0.f,0.f}, a11 = {0.f,0.f,0.f,0.f}, a1d = {0.f,0.f,0.f,0.f};
    const int4 onesv = make_int4(0x3F803F80, 0x3F803F80, 0x3F803F80, 0x3F803F80);
    short8 bones = __builtin_bit_cast(short8, onesv);

    __syncthreads();

    for (int jt4 = 0; jt4 < 8; jt4++) {
        uint4 m0 = mp0[jt4];
        uint4 m1 = mp1[jt4];
        unsigned m0a[4] = {m0.x, m0.y, m0.z, m0.w};
        unsigned m1a[4] = {m1.x, m1.y, m1.z, m1.w};
#pragma unroll
        for (int q = 0; q < 4; q++) {
            int jt = jh * 32 + jt4 * 4 + q;
            const float4* el = (const float4*)&ebl[(jt * 32 + qsh) * 2];
            float4 l0 = el[0], l1 = el[1], l2 = el[2], l3 = el[3];
            int4 blo = bfp[jt * 128];
            int4 bhi = bfp[jt * 128 + 64];
            int4 f0 = pfrag(ea0.x, ea0.y, l0, l1, l2, l3, m0a[q] >> qsh, mlut);
            int4 f1 = pfrag(ea1.x, ea1.y, l0, l1, l2, l3, m1a[q] >> qsh, mlut);
            short8 af0 = __builtin_bit_cast(short8, f0);
            short8 af1 = __builtin_bit_cast(short8, f1);
            short8 b0 = __builtin_bit_cast(short8, blo);
            short8 b1 = __builtin_bit_cast(short8, bhi);
            a00 = __builtin_amdgcn_mfma_f32_16x16x32_bf16(af0, b0, a00, 0, 0, 0);
            a01 = __builtin_amdgcn_mfma_f32_16x16x32_bf16(af0, b1, a01, 0, 0, 0);
            a0d = __builtin_amdgcn_mfma_f32_16x16x32_bf16(af0, bones, a0d, 0, 0, 0);
            a10 = __builtin_amdgcn_mfma_f32_16x16x32_bf16(af1, b0, a10, 0, 0, 0);
            a11 = __builtin_amdgcn_mfma_f32_16x16x32_bf16(af1, b1, a11, 0, 0, 0);
            a1d = __builtin_amdgcn_mfma_f32_16x16x32_bf16(af1, bones, a1d, 0, 0, 0);
        }
    }

    // combine j-halves through LDS
    if (jh) {
#pragma unroll
        for (int r = 0; r < 4; r++) {
            comb[it][r][lane]      = a00[r];
            comb[it][4 + r][lane]  = a01[r];
            comb[it][8 + r][lane]  = a0d[r];
            comb[it][12 + r][lane] = a10[r];
            comb[it][16 + r][lane] = a11[r];
            comb[it][20 + r][lane] = a1d[r];
        }
    }
    __syncthreads();
    if (jh) return;
#pragma unroll
    for (int r = 0; r < 4; r++) {
        a00[r] += comb[it][r][lane];
        a01[r] += comb[it][4 + r][lane];
        a0d[r] += comb[it][8 + r][lane];
        a10[r] += comb[it][12 + r][lane];
        a11[r] += comb[it][16 + r][lane];
        a1d[r] += comb[it][20 + r][lane];
    }

    // epilogue: C/D layout col=lane&15, row=quad*4+reg; a*d[r] = row denominator
    float* op = out + ((size_t)(b * NSZ) + iw) * (HH * ODIM) + h * ODIM + col;
#pragma unroll
    for (int r = 0; r < 4; r++) {
        int row = quad * 4 + r;
        float inv0 = 1.0f / a0d[r];
        float inv1 = 1.0f / a1d[r];
        op[(size_t)row * (HH * ODIM)]           = fmaxf(a00[r] * inv0, 0.f);
        op[(size_t)row * (HH * ODIM) + 16]      = fmaxf(a01[r] * inv0, 0.f);
        op[(size_t)(row + 16) * (HH * ODIM)]      = fmaxf(a10[r] * inv1, 0.f);
        op[(size_t)(row + 16) * (HH * ODIM) + 16] = fmaxf(a11[r] * inv1, 0.f);
    }
}

extern "C" void kernel_launch(void* const* d_in, const int* in_sizes, int n_in,
                              void* d_out, int out_size, void* d_ws, size_t ws_size,
                              hipStream_t stream) {
    const float* x     = (const float*)d_in[0];
    const float* adj   = (const float*)d_in[1];
    const float* W     = (const float*)d_in[2];
    const float* a_src = (const float*)d_in[3];
    const float* a_dst = (const float*)d_in[4];
    float* out = (float*)d_out;

    float* ws = (float*)d_ws;
    float2* eap    = (float2*)(ws + WS_EAP);
    float2* ebp    = (float2*)(ws + WS_EBP);
    unsigned* adjb = (unsigned*)(ws + WS_ADJB);
    int4* whf      = (int4*)(ws + WS_WHF);

    // fused prep: 16384 adj-bitmask blocks + 1024 MFMA-projection blocks
    k_prep<<<dim3(16384 + 1024), dim3(256), 0, stream>>>(x, adj, W, a_src, a_dst,
                                                         adjb, whf, eap, ebp);
    // fused masked softmax + MFMA aggregation: 1024 blocks x 4 waves
    k_gat<<<dim3(BB * HH * (NSZ / 64)), dim3(256), 0, stream>>>(whf, eap, ebp, adjb, out);
}